// Round 6
// baseline (138.748 us; speedup 1.0000x reference)
//
#include <hip/hip_runtime.h>
#include <hip/hip_bf16.h>

using f32x4 = __attribute__((ext_vector_type(4))) float;
using s16x8 = __attribute__((ext_vector_type(8))) short;
using s16x4 = __attribute__((ext_vector_type(4))) short;

#define B_ 2
#define C_ 256
#define N_ 4096
#define LOG2E 1.4426950408889634f

__device__ inline unsigned short f2bf(float f) {
    union { float f; unsigned u; } x{f};
    unsigned r = x.u + 0x7fffu + ((x.u >> 16) & 1u);
    return (unsigned short)(r >> 16);
}

__device__ inline float bf2f(unsigned short u) {
    union { unsigned u; float f; } x{(unsigned)u << 16};
    return x.f;
}

__device__ inline unsigned cvtpk(float lo, float hi) {
    unsigned r;
    asm("v_cvt_pk_bf16_f32 %0, %1, %2" : "=v"(r) : "v"(lo), "v"(hi));
    return r;
}

__device__ inline void load_lds16(const void* g, void* l) {
    __builtin_amdgcn_global_load_lds((const __attribute__((address_space(1))) void*)g,
                                     (__attribute__((address_space(3))) void*)l, 16, 0, 0);
}

// ---------------- GroupNorm: x (b,c,h,w,d) -> hn_t[b][n][c] bf16 ----------------
__global__ __launch_bounds__(256) void gn_kernel(const float* __restrict__ x,
                                                 const float* __restrict__ gamma,
                                                 const float* __restrict__ beta,
                                                 unsigned short* __restrict__ hn_t) {
    int blk = blockIdx.x;            // b*32 + group
    int b = blk >> 5, grp = blk & 31;
    const float* xb = x + ((size_t)b * C_ + grp * 8) * N_;   // 8 channels x 4096
    int t = threadIdx.x;

    float s = 0.f, sq = 0.f;
    const float4* x4 = (const float4*)xb;
    for (int i = 0; i < 32; ++i) {
        float4 v = x4[t + i * 256];
        s += v.x + v.y + v.z + v.w;
        sq += v.x * v.x + v.y * v.y + v.z * v.z + v.w * v.w;
    }
    for (int off = 32; off; off >>= 1) {
        s += __shfl_down(s, off);
        sq += __shfl_down(sq, off);
    }
    __shared__ float red[2][4];
    int wid = t >> 6;
    if ((t & 63) == 0) { red[0][wid] = s; red[1][wid] = sq; }
    __syncthreads();
    __shared__ float stats[2];
    if (t == 0) {
        float S = red[0][0] + red[0][1] + red[0][2] + red[0][3];
        float Q = red[1][0] + red[1][1] + red[1][2] + red[1][3];
        float mean = S / 32768.f;
        float var = Q / 32768.f - mean * mean;
        stats[0] = mean;
        stats[1] = rsqrtf(var + 1e-6f);
    }
    __syncthreads();
    float mean = stats[0], rstd = stats[1];

    float gm[8], bt[8];
    for (int j = 0; j < 8; ++j) {
        gm[j] = gamma[grp * 8 + j] * rstd;
        bt[j] = beta[grp * 8 + j] - mean * gm[j];
    }
    unsigned short* outp = hn_t + (size_t)b * N_ * C_ + grp * 8;
    for (int i = 0; i < 16; ++i) {
        int n = t + i * 256;
        s16x8 pk;
        for (int j = 0; j < 8; ++j) {
            float v = xb[(size_t)j * N_ + n];
            pk[j] = (short)f2bf(v * gm[j] + bt[j]);
        }
        *(s16x8*)(outp + (size_t)n * C_) = pk;
    }
}

// ---------------- W f32 -> bf16 (4 matrices) ----------------
__global__ __launch_bounds__(256) void wcvt_kernel(const float* __restrict__ wq,
                                                   const float* __restrict__ wk,
                                                   const float* __restrict__ wv,
                                                   const float* __restrict__ wp,
                                                   unsigned short* __restrict__ wbf) {
    int g = blockIdx.y;
    const float* src = g == 0 ? wq : g == 1 ? wk : g == 2 ? wv : wp;
    int idx = (blockIdx.x * 256 + threadIdx.x) * 4;
    float4 v = *(const float4*)(src + idx);
    s16x4 pk;
    pk[0] = (short)f2bf(v.x); pk[1] = (short)f2bf(v.y);
    pk[2] = (short)f2bf(v.z); pk[3] = (short)f2bf(v.w);
    *(s16x4*)(wbf + g * 65536 + idx) = pk;
}

// ---------------- GEMM core: 128o x 64n tile, BK=64, dbuf, global_load_lds ----------------
__device__ inline void gemm_core(const unsigned short* __restrict__ Wg,
                                 const unsigned short* __restrict__ Bg,
                                 int o0, int n0, int t, f32x4 (&acc)[4][2],
                                 unsigned short (*At)[128 * 64], unsigned short (*Bt)[64 * 64]) {
    int lane = t & 63, w = t >> 6, l15 = lane & 15, lg = lane >> 4;
    int wo = (w >> 1) * 64, wn = (w & 1) * 32;
    int aoff[4], boff[2];
    for (int i = 0; i < 4; ++i) {
        int p = i * 4096 + t * 16;
        int y = p ^ (((p >> 7) & 7) << 4);
        aoff[i] = (o0 + (y >> 7)) * 512 + (y & 127);
    }
    for (int i = 0; i < 2; ++i) {
        int p = i * 4096 + t * 16;
        int y = p ^ (((p >> 7) & 7) << 4);
        boff[i] = (n0 + (y >> 7)) * 512 + (y & 127);
    }
    const char* Wc = (const char*)Wg;
    const char* Bc = (const char*)Bg;
    int cur = 0;
    for (int i = 0; i < 4; ++i)
        load_lds16(Wc + aoff[i], (char*)At[0] + i * 4096 + w * 1024);
    for (int i = 0; i < 2; ++i)
        load_lds16(Bc + boff[i], (char*)Bt[0] + i * 4096 + w * 1024);
    __syncthreads();
    for (int s = 0; s < 4; ++s) {
        if (s < 3) {
            int k2 = (s + 1) * 128;   // k0 * 2 bytes
            for (int i = 0; i < 4; ++i)
                load_lds16(Wc + aoff[i] + k2, (char*)At[cur ^ 1] + i * 4096 + w * 1024);
            for (int i = 0; i < 2; ++i)
                load_lds16(Bc + boff[i] + k2, (char*)Bt[cur ^ 1] + i * 4096 + w * 1024);
        }
        const char* Al = (const char*)At[cur];
        const char* Bl = (const char*)Bt[cur];
        for (int kk = 0; kk < 2; ++kk) {
            s16x8 af[4], bfv[2];
            for (int mi = 0; mi < 4; ++mi) {
                int row = wo + mi * 16 + l15;
                int lo = row * 128 + kk * 64 + lg * 16;
                af[mi] = *(const s16x8*)(Al + (lo ^ ((row & 7) << 4)));
            }
            for (int ni = 0; ni < 2; ++ni) {
                int row = wn + ni * 16 + l15;
                int lo = row * 128 + kk * 64 + lg * 16;
                bfv[ni] = *(const s16x8*)(Bl + (lo ^ ((row & 7) << 4)));
            }
            for (int mi = 0; mi < 4; ++mi)
                for (int ni = 0; ni < 2; ++ni)
                    acc[mi][ni] = __builtin_amdgcn_mfma_f32_16x16x32_bf16(af[mi], bfv[ni], acc[mi][ni], 0, 0, 0);
        }
        __syncthreads();
        cur ^= 1;
    }
}

// ---------------- fused QKV GEMM (z = b*3 + g) ----------------
// Q -> qt [n][c] (scaled by log2e/16); K -> k3t fragment-major pi-permuted;
// V -> v2t [m/32][c][32].
__global__ __launch_bounds__(256) void qkv_gemm_kernel(const unsigned short* __restrict__ wbf,
                                                       const float* __restrict__ bq,
                                                       const float* __restrict__ bk,
                                                       const float* __restrict__ bv,
                                                       const unsigned short* __restrict__ hn,
                                                       unsigned short* __restrict__ qt,
                                                       unsigned short* __restrict__ kt,
                                                       unsigned short* __restrict__ v2t) {
    __shared__ unsigned short At[2][128 * 64];
    __shared__ unsigned short Bt[2][64 * 64];
    int g = blockIdx.z % 3, b = blockIdx.z / 3;
    const float* bias = g == 0 ? bq : g == 1 ? bk : bv;
    float scale = g == 0 ? 0.0625f * LOG2E : 1.0f;
    int o0 = blockIdx.y * 128, n0 = blockIdx.x * 64;
    int t = threadIdx.x;
    const size_t sz = (size_t)N_ * C_;

    f32x4 acc[4][2];
    for (int mi = 0; mi < 4; ++mi)
        for (int ni = 0; ni < 2; ++ni)
            acc[mi][ni] = (f32x4){0.f, 0.f, 0.f, 0.f};
    gemm_core(wbf + g * 65536, hn + b * sz, o0, n0, t, acc, At, Bt);

    int lane = t & 63, w = t >> 6, l15 = lane & 15, lg = lane >> 4;
    int wo = (w >> 1) * 64, wn = (w & 1) * 32;
    for (int mi = 0; mi < 4; ++mi)
        for (int ni = 0; ni < 2; ++ni)
            for (int r = 0; r < 4; ++r) {
                int o = o0 + wo + mi * 16 + lg * 4 + r;
                int n = n0 + wn + ni * 16 + l15;
                float val = (acc[mi][ni][r] + bias[o]) * scale;
                if (g == 0) {
                    qt[b * sz + (size_t)n * C_ + o] = f2bf(val);
                } else if (g == 1) {
                    // slot = pi^-1(n&31): key bits (r=1:0, f=2, lg=4:3) -> s=16f+4lg+r
                    int slot = ((n >> 2) & 1) * 16 + ((n >> 3) & 3) * 4 + (n & 3);
                    kt[b * sz + (size_t)(n >> 5) * 8192 + (o >> 5) * 1024 + slot * 32 + (o & 31)] = f2bf(val);
                } else {
                    v2t[b * sz + (size_t)(n >> 5) * 8192 + o * 32 + (n & 31)] = f2bf(val);
                }
            }
}

// ---------------- output projection GEMM + residual ----------------
__global__ __launch_bounds__(256) void proj_gemm_kernel(const unsigned short* __restrict__ wbf,
                                                        const float* __restrict__ bp,
                                                        const unsigned short* __restrict__ ao,
                                                        const float* __restrict__ x,
                                                        float* __restrict__ out) {
    __shared__ unsigned short At[2][128 * 64];
    __shared__ unsigned short Bt[2][64 * 64];
    int b = blockIdx.z;
    int o0 = blockIdx.y * 128, n0 = blockIdx.x * 64;
    int t = threadIdx.x;
    const size_t sz = (size_t)N_ * C_;

    f32x4 acc[4][2];
    for (int mi = 0; mi < 4; ++mi)
        for (int ni = 0; ni < 2; ++ni)
            acc[mi][ni] = (f32x4){0.f, 0.f, 0.f, 0.f};
    gemm_core(wbf + 3 * 65536, ao + b * sz, o0, n0, t, acc, At, Bt);

    int lane = t & 63, w = t >> 6, l15 = lane & 15, lg = lane >> 4;
    int wo = (w >> 1) * 64, wn = (w & 1) * 32;
    for (int mi = 0; mi < 4; ++mi)
        for (int ni = 0; ni < 2; ++ni)
            for (int r = 0; r < 4; ++r) {
                int o = o0 + wo + mi * 16 + lg * 4 + r;
                int n = n0 + wn + ni * 16 + l15;
                size_t idx = b * sz + (size_t)o * N_ + n;
                out[idx] = x[idx] + acc[mi][ni][r] + bp[o];
            }
}

// ---------------- Flash attention, KV-split, LDS-free, L2-streaming ----------------
// qt: [b][n][c] (Q scaled by log2e/16). k3t: [b][m/32][c/32][32 slot][32 c]
// (slot s holds key m0+pi(s), pi(s)=8*((s>>2)&3)+4*((s>>4)&1)+(s&3)).
// v2t: [b][m/32][c][32]. Every MFMA fragment load is a contiguous coalesced
// 1KB wave-read served from L2. Each wave owns 32 q-rows; no LDS, no barriers.
__global__ __launch_bounds__(256, 2) void attn_partial_kernel(const unsigned short* __restrict__ qt,
                                                              const unsigned short* __restrict__ k3t,
                                                              const unsigned short* __restrict__ v2t,
                                                              unsigned short* __restrict__ Opart,
                                                              float* __restrict__ ml,
                                                              int kvlen) {
    int b = blockIdx.z, split = blockIdx.y, nsplit = gridDim.y;
    int t = threadIdx.x, lane = t & 63, w = t >> 6, l15 = lane & 15, lg = lane >> 4;
    int n0 = (blockIdx.x * 4 + w) * 32;       // this wave's 32 query rows
    const size_t off = (size_t)b * N_ * C_;
    const unsigned short* Q = qt + off;
    const unsigned short* Kb = k3t + off;
    const unsigned short* Vb = v2t + off;

    s16x8 q[2][8];
    for (int qf = 0; qf < 2; ++qf)
        for (int kc = 0; kc < 8; ++kc)
            q[qf][kc] = *(const s16x8*)(Q + (size_t)(n0 + qf * 16 + l15) * C_ + kc * 32 + lg * 8);

    f32x4 O[2][16];
    for (int qf = 0; qf < 2; ++qf)
        for (int i = 0; i < 16; ++i) O[qf][i] = (f32x4){0.f, 0.f, 0.f, 0.f};
    float mrun[2] = {-1e30f, -1e30f};
    float lsum[2] = {0.f, 0.f};

    int niter = kvlen >> 5;
    int tile0 = (split * kvlen) >> 5;
    for (int it = 0; it < niter; ++it) {
        const unsigned short* kb = Kb + (size_t)(tile0 + it) * 8192;
        const unsigned short* vb = Vb + (size_t)(tile0 + it) * 8192;

        // S^T = K' x Q : S[qf][f] lane holds q=l15, key pi(f*16+lg*4+r)=8lg+4f+r
        f32x4 S[2][2];
        for (int qf = 0; qf < 2; ++qf)
            for (int f = 0; f < 2; ++f) S[qf][f] = (f32x4){0.f, 0.f, 0.f, 0.f};
        for (int kc = 0; kc < 8; ++kc) {
            s16x8 k0 = *(const s16x8*)(kb + kc * 1024 + l15 * 32 + lg * 8);
            s16x8 k1 = *(const s16x8*)(kb + kc * 1024 + (16 + l15) * 32 + lg * 8);
            S[0][0] = __builtin_amdgcn_mfma_f32_16x16x32_bf16(k0, q[0][kc], S[0][0], 0, 0, 0);
            S[0][1] = __builtin_amdgcn_mfma_f32_16x16x32_bf16(k1, q[0][kc], S[0][1], 0, 0, 0);
            S[1][0] = __builtin_amdgcn_mfma_f32_16x16x32_bf16(k0, q[1][kc], S[1][0], 0, 0, 0);
            S[1][1] = __builtin_amdgcn_mfma_f32_16x16x32_bf16(k1, q[1][kc], S[1][1], 0, 0, 0);
        }

        // per-qf row max (8 in-lane + cross-lane-group)
        float mx[2];
        bool ok = true;
        for (int qf = 0; qf < 2; ++qf) {
            float m = fmaxf(fmaxf(fmaxf(S[qf][0][0], S[qf][0][1]), fmaxf(S[qf][0][2], S[qf][0][3])),
                            fmaxf(fmaxf(S[qf][1][0], S[qf][1][1]), fmaxf(S[qf][1][2], S[qf][1][3])));
            m = fmaxf(m, __shfl_xor(m, 16));
            m = fmaxf(m, __shfl_xor(m, 32));
            mx[qf] = m;
            ok = ok && (m <= mrun[qf] + 11.0f);
        }
        if (!__all(ok)) {
            for (int qf = 0; qf < 2; ++qf) {
                float newm = fmaxf(mrun[qf], mx[qf]);
                float alpha = __builtin_amdgcn_exp2f(mrun[qf] - newm);
                mrun[qf] = newm;
                lsum[qf] *= alpha;
                float a0 = __shfl(alpha, lg * 4 + 0);
                float a1 = __shfl(alpha, lg * 4 + 1);
                float a2 = __shfl(alpha, lg * 4 + 2);
                float a3 = __shfl(alpha, lg * 4 + 3);
                for (int i = 0; i < 16; ++i) {
                    O[qf][i][0] *= a0; O[qf][i][1] *= a1;
                    O[qf][i][2] *= a2; O[qf][i][3] *= a3;
                }
            }
        }

        // P = 2^(S-m): in-register A-frags + row sums
        s16x8 pa[2];
        for (int qf = 0; qf < 2; ++qf) {
            float p0 = __builtin_amdgcn_exp2f(S[qf][0][0] - mrun[qf]);
            float p1 = __builtin_amdgcn_exp2f(S[qf][0][1] - mrun[qf]);
            float p2 = __builtin_amdgcn_exp2f(S[qf][0][2] - mrun[qf]);
            float p3 = __builtin_amdgcn_exp2f(S[qf][0][3] - mrun[qf]);
            float p4 = __builtin_amdgcn_exp2f(S[qf][1][0] - mrun[qf]);
            float p5 = __builtin_amdgcn_exp2f(S[qf][1][1] - mrun[qf]);
            float p6 = __builtin_amdgcn_exp2f(S[qf][1][2] - mrun[qf]);
            float p7 = __builtin_amdgcn_exp2f(S[qf][1][3] - mrun[qf]);
            float ps = ((p0 + p1) + (p2 + p3)) + ((p4 + p5) + (p6 + p7));
            ps += __shfl_xor(ps, 16);
            ps += __shfl_xor(ps, 32);
            lsum[qf] += ps;
            union { unsigned u[4]; s16x8 v; } pk;
            pk.u[0] = cvtpk(p0, p1);
            pk.u[1] = cvtpk(p2, p3);
            pk.u[2] = cvtpk(p4, p5);
            pk.u[3] = cvtpk(p6, p7);
            pa[qf] = pk.v;
        }

        // O += P * V  (V B-frags shared across the two q-fragments)
        for (int cb = 0; cb < 16; ++cb) {
            s16x8 vf = *(const s16x8*)(vb + (cb * 16 + l15) * 32 + lg * 8);
            O[0][cb] = __builtin_amdgcn_mfma_f32_16x16x32_bf16(pa[0], vf, O[0][cb], 0, 0, 0);
            O[1][cb] = __builtin_amdgcn_mfma_f32_16x16x32_bf16(pa[1], vf, O[1][cb], 0, 0, 0);
        }
    }

    unsigned short* Ob = Opart + (size_t)(b * nsplit + split) * N_ * C_;
    float* mlb = ml + (size_t)(b * nsplit + split) * N_ * 2;
    for (int qf = 0; qf < 2; ++qf)
        for (int cb = 0; cb < 16; ++cb)
            for (int r = 0; r < 4; ++r)
                Ob[(size_t)(n0 + qf * 16 + lg * 4 + r) * C_ + cb * 16 + l15] = f2bf(O[qf][cb][r]);
    if (lane < 16)
        for (int qf = 0; qf < 2; ++qf) {
            int n = n0 + qf * 16 + lane;
            mlb[n * 2] = mrun[qf];
            mlb[n * 2 + 1] = lsum[qf];
        }
}

// ---------------- merge partials -> ao bf16 [b][n][c] ----------------
__global__ __launch_bounds__(256) void attn_merge_kernel(const unsigned short* __restrict__ Opart,
                                                         const float* __restrict__ ml,
                                                         unsigned short* __restrict__ ao,
                                                         int nsplit) {
    int b = blockIdx.y, n = blockIdx.x, c = threadIdx.x;
    float M = -1e30f;
    for (int s = 0; s < nsplit; ++s)
        M = fmaxf(M, ml[((size_t)(b * nsplit + s) * N_ + n) * 2]);
    float L = 0.f, o = 0.f;
    for (int s = 0; s < nsplit; ++s) {
        const float* mlp = ml + ((size_t)(b * nsplit + s) * N_ + n) * 2;
        float wgt = __builtin_amdgcn_exp2f(mlp[0] - M);
        L += mlp[1] * wgt;
        o += bf2f(Opart[((size_t)(b * nsplit + s) * N_ + n) * C_ + c]) * wgt;
    }
    ao[((size_t)b * N_ + n) * C_ + c] = f2bf(o / L);
}

extern "C" void kernel_launch(void* const* d_in, const int* in_sizes, int n_in,
                              void* d_out, int out_size, void* d_ws, size_t ws_size,
                              hipStream_t stream) {
    const float* x = (const float*)d_in[0];
    const float* gamma = (const float*)d_in[1];
    const float* beta = (const float*)d_in[2];
    const float* wq = (const float*)d_in[3];
    const float* bq = (const float*)d_in[4];
    const float* wk = (const float*)d_in[5];
    const float* bk = (const float*)d_in[6];
    const float* wv = (const float*)d_in[7];
    const float* bv = (const float*)d_in[8];
    const float* wp = (const float*)d_in[9];
    const float* bp = (const float*)d_in[10];
    float* out = (float*)d_out;

    const size_t sz = (size_t)B_ * N_ * C_;
    unsigned short* hn = (unsigned short*)d_ws;  // [b][n][c]
    unsigned short* qt = hn + sz;                // [b][n][c], scaled by log2e/16
    unsigned short* kt = qt + sz;                // k3t fragment-major layout
    unsigned short* v2t = kt + sz;               // [b][m/32][c][32]
    unsigned short* ao = v2t + sz;               // [b][n][c]
    unsigned short* wbf = ao + sz;               // 4 x 256 x 256 bf16
    unsigned short* Opart = wbf + 4 * 65536;     // [b][s][n][c] bf16, unnormalized
    int nsplit = 8;
    while (nsplit > 1 &&
           (5 * sz + 262144 + (size_t)nsplit * sz) * 2 + (size_t)nsplit * B_ * N_ * 8 > ws_size)
        nsplit >>= 1;
    float* ml = (float*)(Opart + (size_t)nsplit * sz);   // [b][s][n][2] (log2-domain m, l)

    hipLaunchKernelGGL(gn_kernel, dim3(64), dim3(256), 0, stream, x, gamma, beta, hn);
    hipLaunchKernelGGL(wcvt_kernel, dim3(64, 4), dim3(256), 0, stream, wq, wk, wv, wp, wbf);
    hipLaunchKernelGGL(qkv_gemm_kernel, dim3(64, 2, 6), dim3(256), 0, stream,
                       wbf, bq, bk, bv, hn, qt, kt, v2t);
    hipLaunchKernelGGL(attn_partial_kernel, dim3(32, nsplit, 2), dim3(256), 0, stream,
                       qt, kt, v2t, Opart, ml, N_ / nsplit);
    hipLaunchKernelGGL(attn_merge_kernel, dim3(N_, 2), dim3(256), 0, stream, Opart, ml, ao, nsplit);
    hipLaunchKernelGGL(proj_gemm_kernel, dim3(64, 2, 2), dim3(256), 0, stream, wbf, bp, ao, x, out);
}

// Round 7
// 102.766 us; speedup vs baseline: 1.3501x; 1.3501x over previous
//
#include <hip/hip_runtime.h>
#include <hip/hip_bf16.h>

using f32x4 = __attribute__((ext_vector_type(4))) float;
using s16x8 = __attribute__((ext_vector_type(8))) short;
using s16x4 = __attribute__((ext_vector_type(4))) short;

#define B_ 2
#define C_ 256
#define N_ 4096
#define LOG2E 1.4426950408889634f

__device__ inline unsigned short f2bf(float f) {
    union { float f; unsigned u; } x{f};
    unsigned r = x.u + 0x7fffu + ((x.u >> 16) & 1u);
    return (unsigned short)(r >> 16);
}

__device__ inline float bf2f(unsigned short u) {
    union { unsigned u; float f; } x{(unsigned)u << 16};
    return x.f;
}

__device__ inline unsigned cvtpk(float lo, float hi) {
    unsigned r;
    asm("v_cvt_pk_bf16_f32 %0, %1, %2" : "=v"(r) : "v"(lo), "v"(hi));
    return r;
}

__device__ inline void load_lds16(const void* g, void* l) {
    __builtin_amdgcn_global_load_lds((const __attribute__((address_space(1))) void*)g,
                                     (__attribute__((address_space(3))) void*)l, 16, 0, 0);
}

// ---------------- GroupNorm: x (b,c,h,w,d) -> hn_t[b][n][c] bf16 ----------------
__global__ __launch_bounds__(256) void gn_kernel(const float* __restrict__ x,
                                                 const float* __restrict__ gamma,
                                                 const float* __restrict__ beta,
                                                 unsigned short* __restrict__ hn_t) {
    int blk = blockIdx.x;            // b*32 + group
    int b = blk >> 5, grp = blk & 31;
    const float* xb = x + ((size_t)b * C_ + grp * 8) * N_;   // 8 channels x 4096
    int t = threadIdx.x;

    float s = 0.f, sq = 0.f;
    const float4* x4 = (const float4*)xb;
    for (int i = 0; i < 32; ++i) {
        float4 v = x4[t + i * 256];
        s += v.x + v.y + v.z + v.w;
        sq += v.x * v.x + v.y * v.y + v.z * v.z + v.w * v.w;
    }
    for (int off = 32; off; off >>= 1) {
        s += __shfl_down(s, off);
        sq += __shfl_down(sq, off);
    }
    __shared__ float red[2][4];
    int wid = t >> 6;
    if ((t & 63) == 0) { red[0][wid] = s; red[1][wid] = sq; }
    __syncthreads();
    __shared__ float stats[2];
    if (t == 0) {
        float S = red[0][0] + red[0][1] + red[0][2] + red[0][3];
        float Q = red[1][0] + red[1][1] + red[1][2] + red[1][3];
        float mean = S / 32768.f;
        float var = Q / 32768.f - mean * mean;
        stats[0] = mean;
        stats[1] = rsqrtf(var + 1e-6f);
    }
    __syncthreads();
    float mean = stats[0], rstd = stats[1];

    float gm[8], bt[8];
    for (int j = 0; j < 8; ++j) {
        gm[j] = gamma[grp * 8 + j] * rstd;
        bt[j] = beta[grp * 8 + j] - mean * gm[j];
    }
    unsigned short* outp = hn_t + (size_t)b * N_ * C_ + grp * 8;
    for (int i = 0; i < 16; ++i) {
        int n = t + i * 256;
        s16x8 pk;
        for (int j = 0; j < 8; ++j) {
            float v = xb[(size_t)j * N_ + n];
            pk[j] = (short)f2bf(v * gm[j] + bt[j]);
        }
        *(s16x8*)(outp + (size_t)n * C_) = pk;
    }
}

// ---------------- W f32 -> bf16 (4 matrices) ----------------
__global__ __launch_bounds__(256) void wcvt_kernel(const float* __restrict__ wq,
                                                   const float* __restrict__ wk,
                                                   const float* __restrict__ wv,
                                                   const float* __restrict__ wp,
                                                   unsigned short* __restrict__ wbf) {
    int g = blockIdx.y;
    const float* src = g == 0 ? wq : g == 1 ? wk : g == 2 ? wv : wp;
    int idx = (blockIdx.x * 256 + threadIdx.x) * 4;
    float4 v = *(const float4*)(src + idx);
    s16x4 pk;
    pk[0] = (short)f2bf(v.x); pk[1] = (short)f2bf(v.y);
    pk[2] = (short)f2bf(v.z); pk[3] = (short)f2bf(v.w);
    *(s16x4*)(wbf + g * 65536 + idx) = pk;
}

// ---------------- GEMM core: 128o x 64n tile, BK=64, dbuf, global_load_lds ----------------
__device__ inline void gemm_core(const unsigned short* __restrict__ Wg,
                                 const unsigned short* __restrict__ Bg,
                                 int o0, int n0, int t, f32x4 (&acc)[4][2],
                                 unsigned short (*At)[128 * 64], unsigned short (*Bt)[64 * 64]) {
    int lane = t & 63, w = t >> 6, l15 = lane & 15, lg = lane >> 4;
    int wo = (w >> 1) * 64, wn = (w & 1) * 32;
    int aoff[4], boff[2];
    for (int i = 0; i < 4; ++i) {
        int p = i * 4096 + t * 16;
        int y = p ^ (((p >> 7) & 7) << 4);
        aoff[i] = (o0 + (y >> 7)) * 512 + (y & 127);
    }
    for (int i = 0; i < 2; ++i) {
        int p = i * 4096 + t * 16;
        int y = p ^ (((p >> 7) & 7) << 4);
        boff[i] = (n0 + (y >> 7)) * 512 + (y & 127);
    }
    const char* Wc = (const char*)Wg;
    const char* Bc = (const char*)Bg;
    int cur = 0;
    for (int i = 0; i < 4; ++i)
        load_lds16(Wc + aoff[i], (char*)At[0] + i * 4096 + w * 1024);
    for (int i = 0; i < 2; ++i)
        load_lds16(Bc + boff[i], (char*)Bt[0] + i * 4096 + w * 1024);
    __syncthreads();
    for (int s = 0; s < 4; ++s) {
        if (s < 3) {
            int k2 = (s + 1) * 128;   // k0 * 2 bytes
            for (int i = 0; i < 4; ++i)
                load_lds16(Wc + aoff[i] + k2, (char*)At[cur ^ 1] + i * 4096 + w * 1024);
            for (int i = 0; i < 2; ++i)
                load_lds16(Bc + boff[i] + k2, (char*)Bt[cur ^ 1] + i * 4096 + w * 1024);
        }
        const char* Al = (const char*)At[cur];
        const char* Bl = (const char*)Bt[cur];
        for (int kk = 0; kk < 2; ++kk) {
            s16x8 af[4], bfv[2];
            for (int mi = 0; mi < 4; ++mi) {
                int row = wo + mi * 16 + l15;
                int lo = row * 128 + kk * 64 + lg * 16;
                af[mi] = *(const s16x8*)(Al + (lo ^ ((row & 7) << 4)));
            }
            for (int ni = 0; ni < 2; ++ni) {
                int row = wn + ni * 16 + l15;
                int lo = row * 128 + kk * 64 + lg * 16;
                bfv[ni] = *(const s16x8*)(Bl + (lo ^ ((row & 7) << 4)));
            }
            for (int mi = 0; mi < 4; ++mi)
                for (int ni = 0; ni < 2; ++ni)
                    acc[mi][ni] = __builtin_amdgcn_mfma_f32_16x16x32_bf16(af[mi], bfv[ni], acc[mi][ni], 0, 0, 0);
        }
        __syncthreads();
        cur ^= 1;
    }
}

// ---------------- fused QKV GEMM (z = b*3 + g) ----------------
// Q -> qt [n][c] (scaled by log2e/16); K -> k3t fragment-major pi-permuted;
// V -> v2t [m/32][c][32].
__global__ __launch_bounds__(256) void qkv_gemm_kernel(const unsigned short* __restrict__ wbf,
                                                       const float* __restrict__ bq,
                                                       const float* __restrict__ bk,
                                                       const float* __restrict__ bv,
                                                       const unsigned short* __restrict__ hn,
                                                       unsigned short* __restrict__ qt,
                                                       unsigned short* __restrict__ kt,
                                                       unsigned short* __restrict__ v2t) {
    __shared__ unsigned short At[2][128 * 64];
    __shared__ unsigned short Bt[2][64 * 64];
    int g = blockIdx.z % 3, b = blockIdx.z / 3;
    const float* bias = g == 0 ? bq : g == 1 ? bk : bv;
    float scale = g == 0 ? 0.0625f * LOG2E : 1.0f;
    int o0 = blockIdx.y * 128, n0 = blockIdx.x * 64;
    int t = threadIdx.x;
    const size_t sz = (size_t)N_ * C_;

    f32x4 acc[4][2];
    for (int mi = 0; mi < 4; ++mi)
        for (int ni = 0; ni < 2; ++ni)
            acc[mi][ni] = (f32x4){0.f, 0.f, 0.f, 0.f};
    gemm_core(wbf + g * 65536, hn + b * sz, o0, n0, t, acc, At, Bt);

    int lane = t & 63, w = t >> 6, l15 = lane & 15, lg = lane >> 4;
    int wo = (w >> 1) * 64, wn = (w & 1) * 32;
    for (int mi = 0; mi < 4; ++mi)
        for (int ni = 0; ni < 2; ++ni)
            for (int r = 0; r < 4; ++r) {
                int o = o0 + wo + mi * 16 + lg * 4 + r;
                int n = n0 + wn + ni * 16 + l15;
                float val = (acc[mi][ni][r] + bias[o]) * scale;
                if (g == 0) {
                    qt[b * sz + (size_t)n * C_ + o] = f2bf(val);
                } else if (g == 1) {
                    // slot = pi^-1(n&31): key bits (r=1:0, f=2, lg=4:3) -> s=16f+4lg+r
                    int slot = ((n >> 2) & 1) * 16 + ((n >> 3) & 3) * 4 + (n & 3);
                    kt[b * sz + (size_t)(n >> 5) * 8192 + (o >> 5) * 1024 + slot * 32 + (o & 31)] = f2bf(val);
                } else {
                    v2t[b * sz + (size_t)(n >> 5) * 8192 + o * 32 + (n & 31)] = f2bf(val);
                }
            }
}

// ---------------- output projection GEMM + residual ----------------
__global__ __launch_bounds__(256) void proj_gemm_kernel(const unsigned short* __restrict__ wbf,
                                                        const float* __restrict__ bp,
                                                        const unsigned short* __restrict__ ao,
                                                        const float* __restrict__ x,
                                                        float* __restrict__ out) {
    __shared__ unsigned short At[2][128 * 64];
    __shared__ unsigned short Bt[2][64 * 64];
    int b = blockIdx.z;
    int o0 = blockIdx.y * 128, n0 = blockIdx.x * 64;
    int t = threadIdx.x;
    const size_t sz = (size_t)N_ * C_;

    f32x4 acc[4][2];
    for (int mi = 0; mi < 4; ++mi)
        for (int ni = 0; ni < 2; ++ni)
            acc[mi][ni] = (f32x4){0.f, 0.f, 0.f, 0.f};
    gemm_core(wbf + 3 * 65536, ao + b * sz, o0, n0, t, acc, At, Bt);

    int lane = t & 63, w = t >> 6, l15 = lane & 15, lg = lane >> 4;
    int wo = (w >> 1) * 64, wn = (w & 1) * 32;
    for (int mi = 0; mi < 4; ++mi)
        for (int ni = 0; ni < 2; ++ni)
            for (int r = 0; r < 4; ++r) {
                int o = o0 + wo + mi * 16 + lg * 4 + r;
                int n = n0 + wn + ni * 16 + l15;
                size_t idx = b * sz + (size_t)o * N_ + n;
                out[idx] = x[idx] + acc[mi][ni][r] + bp[o];
            }
}

// ---------------- Flash attention: KV-split + LDS-staged fragment-major K/V ----------------
// qt: [b][n][c] (Q scaled by log2e/16). k3t: [b][m/32][c/32][32 slot][32 c]
// (slot s holds key m0+pi(s), pi(s)=8*((s>>2)&3)+4*((s>>4)&1)+(s&3)).
// v2t: [b][m/32][c][32]. Tiles are 16KB contiguous -> staging is an identity
// global_load_lds copy; all LDS fragment reads are contiguous 1KB wave-reads
// (conflict-free). Each wave owns 32 q-rows; K/V shared by 4 waves via LDS.
__global__ __launch_bounds__(256, 2) void attn_partial_kernel(const unsigned short* __restrict__ qt,
                                                              const unsigned short* __restrict__ k3t,
                                                              const unsigned short* __restrict__ v2t,
                                                              unsigned short* __restrict__ Opart,
                                                              float* __restrict__ ml,
                                                              int kvlen) {
    int b = blockIdx.z, split = blockIdx.y, nsplit = gridDim.y;
    int t = threadIdx.x, lane = t & 63, w = t >> 6, l15 = lane & 15, lg = lane >> 4;
    int n0 = (blockIdx.x * 4 + w) * 32;       // this wave's 32 query rows
    const size_t off = (size_t)b * N_ * C_;
    const unsigned short* Q = qt + off;
    const char* Kg = (const char*)(k3t + off);
    const char* Vg = (const char*)(v2t + off);

    __shared__ char Ktile[2][16384];
    __shared__ char Vtile[2][16384];

    s16x8 q[2][8];
    for (int qf = 0; qf < 2; ++qf)
        for (int kc = 0; kc < 8; ++kc)
            q[qf][kc] = *(const s16x8*)(Q + (size_t)(n0 + qf * 16 + l15) * C_ + kc * 32 + lg * 8);

    f32x4 O[2][16];
    for (int qf = 0; qf < 2; ++qf)
        for (int i = 0; i < 16; ++i) O[qf][i] = (f32x4){0.f, 0.f, 0.f, 0.f};
    float mrun[2] = {-1e30f, -1e30f};
    float lsum[2] = {0.f, 0.f};

    auto stage = [&](int buf, int tile) {
        const char* kg = Kg + (size_t)tile * 16384;
        const char* vg = Vg + (size_t)tile * 16384;
        for (int i = 0; i < 4; ++i)
            load_lds16(kg + i * 4096 + t * 16, Ktile[buf] + i * 4096 + w * 1024);
        for (int i = 0; i < 4; ++i)
            load_lds16(vg + i * 4096 + t * 16, Vtile[buf] + i * 4096 + w * 1024);
    };

    int niter = kvlen >> 5;
    int tile0 = (split * kvlen) >> 5;
    int cur = 0;
    stage(0, tile0);
    __syncthreads();   // implicit vmcnt(0): tile 0 resident

    for (int it = 0; it < niter; ++it) {
        if (it + 1 < niter) stage(cur ^ 1, tile0 + it + 1);   // async prefetch

        const char* kb = Ktile[cur];
        const char* vb = Vtile[cur];

        // S^T = K' x Q : S[qf][f] lane holds q=l15, key pi(f*16+lg*4+r)=8lg+4f+r
        f32x4 S[2][2];
        for (int qf = 0; qf < 2; ++qf)
            for (int f = 0; f < 2; ++f) S[qf][f] = (f32x4){0.f, 0.f, 0.f, 0.f};
        for (int kc = 0; kc < 8; ++kc) {
            s16x8 k0 = *(const s16x8*)(kb + kc * 2048 + l15 * 64 + lg * 16);
            s16x8 k1 = *(const s16x8*)(kb + kc * 2048 + (16 + l15) * 64 + lg * 16);
            S[0][0] = __builtin_amdgcn_mfma_f32_16x16x32_bf16(k0, q[0][kc], S[0][0], 0, 0, 0);
            S[0][1] = __builtin_amdgcn_mfma_f32_16x16x32_bf16(k1, q[0][kc], S[0][1], 0, 0, 0);
            S[1][0] = __builtin_amdgcn_mfma_f32_16x16x32_bf16(k0, q[1][kc], S[1][0], 0, 0, 0);
            S[1][1] = __builtin_amdgcn_mfma_f32_16x16x32_bf16(k1, q[1][kc], S[1][1], 0, 0, 0);
        }

        // per-qf row max (8 in-lane + cross-lane-group)
        float mx[2];
        bool ok = true;
        for (int qf = 0; qf < 2; ++qf) {
            float m = fmaxf(fmaxf(fmaxf(S[qf][0][0], S[qf][0][1]), fmaxf(S[qf][0][2], S[qf][0][3])),
                            fmaxf(fmaxf(S[qf][1][0], S[qf][1][1]), fmaxf(S[qf][1][2], S[qf][1][3])));
            m = fmaxf(m, __shfl_xor(m, 16));
            m = fmaxf(m, __shfl_xor(m, 32));
            mx[qf] = m;
            ok = ok && (m <= mrun[qf] + 11.0f);
        }
        if (!__all(ok)) {
            for (int qf = 0; qf < 2; ++qf) {
                float newm = fmaxf(mrun[qf], mx[qf]);
                float alpha = __builtin_amdgcn_exp2f(mrun[qf] - newm);
                mrun[qf] = newm;
                lsum[qf] *= alpha;
                float a0 = __shfl(alpha, lg * 4 + 0);
                float a1 = __shfl(alpha, lg * 4 + 1);
                float a2 = __shfl(alpha, lg * 4 + 2);
                float a3 = __shfl(alpha, lg * 4 + 3);
                for (int i = 0; i < 16; ++i) {
                    O[qf][i][0] *= a0; O[qf][i][1] *= a1;
                    O[qf][i][2] *= a2; O[qf][i][3] *= a3;
                }
            }
        }

        // P = 2^(S-m): in-register A-frags + row sums
        s16x8 pa[2];
        for (int qf = 0; qf < 2; ++qf) {
            float p0 = __builtin_amdgcn_exp2f(S[qf][0][0] - mrun[qf]);
            float p1 = __builtin_amdgcn_exp2f(S[qf][0][1] - mrun[qf]);
            float p2 = __builtin_amdgcn_exp2f(S[qf][0][2] - mrun[qf]);
            float p3 = __builtin_amdgcn_exp2f(S[qf][0][3] - mrun[qf]);
            float p4 = __builtin_amdgcn_exp2f(S[qf][1][0] - mrun[qf]);
            float p5 = __builtin_amdgcn_exp2f(S[qf][1][1] - mrun[qf]);
            float p6 = __builtin_amdgcn_exp2f(S[qf][1][2] - mrun[qf]);
            float p7 = __builtin_amdgcn_exp2f(S[qf][1][3] - mrun[qf]);
            float ps = ((p0 + p1) + (p2 + p3)) + ((p4 + p5) + (p6 + p7));
            ps += __shfl_xor(ps, 16);
            ps += __shfl_xor(ps, 32);
            lsum[qf] += ps;
            union { unsigned u[4]; s16x8 v; } pk;
            pk.u[0] = cvtpk(p0, p1);
            pk.u[1] = cvtpk(p2, p3);
            pk.u[2] = cvtpk(p4, p5);
            pk.u[3] = cvtpk(p6, p7);
            pa[qf] = pk.v;
        }

        // O += P * V  (V B-frags from LDS, shared across the two q-fragments)
        for (int cb = 0; cb < 16; ++cb) {
            s16x8 vf = *(const s16x8*)(vb + (cb * 16 + l15) * 64 + lg * 16);
            O[0][cb] = __builtin_amdgcn_mfma_f32_16x16x32_bf16(pa[0], vf, O[0][cb], 0, 0, 0);
            O[1][cb] = __builtin_amdgcn_mfma_f32_16x16x32_bf16(pa[1], vf, O[1][cb], 0, 0, 0);
        }

        __syncthreads();   // drains vmcnt(0): prefetch done, all waves done with cur
        cur ^= 1;
    }

    unsigned short* Ob = Opart + (size_t)(b * nsplit + split) * N_ * C_;
    float* mlb = ml + (size_t)(b * nsplit + split) * N_ * 2;
    for (int qf = 0; qf < 2; ++qf)
        for (int cb = 0; cb < 16; ++cb)
            for (int r = 0; r < 4; ++r)
                Ob[(size_t)(n0 + qf * 16 + lg * 4 + r) * C_ + cb * 16 + l15] = f2bf(O[qf][cb][r]);
    if (lane < 16)
        for (int qf = 0; qf < 2; ++qf) {
            int n = n0 + qf * 16 + lane;
            mlb[n * 2] = mrun[qf];
            mlb[n * 2 + 1] = lsum[qf];
        }
}

// ---------------- merge partials -> ao bf16 [b][n][c] ----------------
__global__ __launch_bounds__(256) void attn_merge_kernel(const unsigned short* __restrict__ Opart,
                                                         const float* __restrict__ ml,
                                                         unsigned short* __restrict__ ao,
                                                         int nsplit) {
    int b = blockIdx.y, n = blockIdx.x, c = threadIdx.x;
    float M = -1e30f;
    for (int s = 0; s < nsplit; ++s)
        M = fmaxf(M, ml[((size_t)(b * nsplit + s) * N_ + n) * 2]);
    float L = 0.f, o = 0.f;
    for (int s = 0; s < nsplit; ++s) {
        const float* mlp = ml + ((size_t)(b * nsplit + s) * N_ + n) * 2;
        float wgt = __builtin_amdgcn_exp2f(mlp[0] - M);
        L += mlp[1] * wgt;
        o += bf2f(Opart[((size_t)(b * nsplit + s) * N_ + n) * C_ + c]) * wgt;
    }
    ao[((size_t)b * N_ + n) * C_ + c] = f2bf(o / L);
}

extern "C" void kernel_launch(void* const* d_in, const int* in_sizes, int n_in,
                              void* d_out, int out_size, void* d_ws, size_t ws_size,
                              hipStream_t stream) {
    const float* x = (const float*)d_in[0];
    const float* gamma = (const float*)d_in[1];
    const float* beta = (const float*)d_in[2];
    const float* wq = (const float*)d_in[3];
    const float* bq = (const float*)d_in[4];
    const float* wk = (const float*)d_in[5];
    const float* bk = (const float*)d_in[6];
    const float* wv = (const float*)d_in[7];
    const float* bv = (const float*)d_in[8];
    const float* wp = (const float*)d_in[9];
    const float* bp = (const float*)d_in[10];
    float* out = (float*)d_out;

    const size_t sz = (size_t)B_ * N_ * C_;
    unsigned short* hn = (unsigned short*)d_ws;  // [b][n][c]
    unsigned short* qt = hn + sz;                // [b][n][c], scaled by log2e/16
    unsigned short* kt = qt + sz;                // k3t fragment-major layout
    unsigned short* v2t = kt + sz;               // [b][m/32][c][32]
    unsigned short* ao = v2t + sz;               // [b][n][c]
    unsigned short* wbf = ao + sz;               // 4 x 256 x 256 bf16
    unsigned short* Opart = wbf + 4 * 65536;     // [b][s][n][c] bf16, unnormalized
    int nsplit = 8;
    while (nsplit > 1 &&
           (5 * sz + 262144 + (size_t)nsplit * sz) * 2 + (size_t)nsplit * B_ * N_ * 8 > ws_size)
        nsplit >>= 1;
    float* ml = (float*)(Opart + (size_t)nsplit * sz);   // [b][s][n][2] (log2-domain m, l)

    hipLaunchKernelGGL(gn_kernel, dim3(64), dim3(256), 0, stream, x, gamma, beta, hn);
    hipLaunchKernelGGL(wcvt_kernel, dim3(64, 4), dim3(256), 0, stream, wq, wk, wv, wp, wbf);
    hipLaunchKernelGGL(qkv_gemm_kernel, dim3(64, 2, 6), dim3(256), 0, stream,
                       wbf, bq, bk, bv, hn, qt, kt, v2t);
    hipLaunchKernelGGL(attn_partial_kernel, dim3(32, nsplit, 2), dim3(256), 0, stream,
                       qt, kt, v2t, Opart, ml, N_ / nsplit);
    hipLaunchKernelGGL(attn_merge_kernel, dim3(N_, 2), dim3(256), 0, stream, Opart, ml, ao, nsplit);
    hipLaunchKernelGGL(proj_gemm_kernel, dim3(64, 2, 2), dim3(256), 0, stream, wbf, bp, ao, x, out);
}

// Round 8
// 99.300 us; speedup vs baseline: 1.3973x; 1.0349x over previous
//
#include <hip/hip_runtime.h>
#include <hip/hip_bf16.h>

using f32x4 = __attribute__((ext_vector_type(4))) float;
using s16x8 = __attribute__((ext_vector_type(8))) short;
using s16x4 = __attribute__((ext_vector_type(4))) short;

#define B_ 2
#define C_ 256
#define N_ 4096
#define LOG2E 1.4426950408889634f

__device__ inline unsigned short f2bf(float f) {
    union { float f; unsigned u; } x{f};
    unsigned r = x.u + 0x7fffu + ((x.u >> 16) & 1u);
    return (unsigned short)(r >> 16);
}

__device__ inline float bf2f(unsigned short u) {
    union { unsigned u; float f; } x{(unsigned)u << 16};
    return x.f;
}

__device__ inline unsigned cvtpk(float lo, float hi) {
    unsigned r;
    asm("v_cvt_pk_bf16_f32 %0, %1, %2" : "=v"(r) : "v"(lo), "v"(hi));
    return r;
}

__device__ inline void load_lds16(const void* g, void* l) {
    __builtin_amdgcn_global_load_lds((const __attribute__((address_space(1))) void*)g,
                                     (__attribute__((address_space(3))) void*)l, 16, 0, 0);
}

// ---------------- GroupNorm pass 1: partial sums, 256 blocks ----------------
// block = b*128 + grp*4 + qtr; each covers 8 channels x 1024 spatial
__global__ __launch_bounds__(256) void gn_stats_kernel(const float* __restrict__ x,
                                                       float* __restrict__ part) {
    int blk = blockIdx.x;
    int qtr = blk & 3, grp = (blk >> 2) & 31, b = blk >> 7;
    const float* xb = x + ((size_t)b * C_ + grp * 8) * N_ + qtr * 1024;
    int t = threadIdx.x;
    float s = 0.f, sq = 0.f;
    for (int j = 0; j < 8; ++j) {
        float4 v = *(const float4*)(xb + (size_t)j * N_ + t * 4);
        s += v.x + v.y + v.z + v.w;
        sq += v.x * v.x + v.y * v.y + v.z * v.z + v.w * v.w;
    }
    for (int off = 32; off; off >>= 1) {
        s += __shfl_down(s, off);
        sq += __shfl_down(sq, off);
    }
    __shared__ float red[2][4];
    int wid = t >> 6;
    if ((t & 63) == 0) { red[0][wid] = s; red[1][wid] = sq; }
    __syncthreads();
    if (t == 0) {
        part[blk * 2 + 0] = red[0][0] + red[0][1] + red[0][2] + red[0][3];
        part[blk * 2 + 1] = red[1][0] + red[1][1] + red[1][2] + red[1][3];
    }
}

// ---------------- GroupNorm pass 2: normalize + write bf16 [n][c] ----------------
__global__ __launch_bounds__(256) void gn_apply_kernel(const float* __restrict__ x,
                                                       const float* __restrict__ gamma,
                                                       const float* __restrict__ beta,
                                                       const float* __restrict__ part,
                                                       unsigned short* __restrict__ hn_t) {
    int blk = blockIdx.x;
    int qtr = blk & 3, grp = (blk >> 2) & 31, b = blk >> 7;
    int base = (blk & ~3) * 2;
    float S = part[base + 0] + part[base + 2] + part[base + 4] + part[base + 6];
    float Q = part[base + 1] + part[base + 3] + part[base + 5] + part[base + 7];
    float mean = S / 32768.f;
    float rstd = rsqrtf(Q / 32768.f - mean * mean + 1e-6f);

    float gm[8], bt[8];
    for (int j = 0; j < 8; ++j) {
        gm[j] = gamma[grp * 8 + j] * rstd;
        bt[j] = beta[grp * 8 + j] - mean * gm[j];
    }
    const float* xb = x + ((size_t)b * C_ + grp * 8) * N_;
    unsigned short* outp = hn_t + (size_t)b * N_ * C_ + grp * 8;
    int t = threadIdx.x;
    for (int i = 0; i < 4; ++i) {
        int n = qtr * 1024 + i * 256 + t;
        s16x8 pk;
        for (int j = 0; j < 8; ++j) {
            float v = xb[(size_t)j * N_ + n];
            pk[j] = (short)f2bf(v * gm[j] + bt[j]);
        }
        *(s16x8*)(outp + (size_t)n * C_) = pk;
    }
}

// ---------------- W f32 -> bf16 (4 matrices) ----------------
__global__ __launch_bounds__(256) void wcvt_kernel(const float* __restrict__ wq,
                                                   const float* __restrict__ wk,
                                                   const float* __restrict__ wv,
                                                   const float* __restrict__ wp,
                                                   unsigned short* __restrict__ wbf) {
    int g = blockIdx.y;
    const float* src = g == 0 ? wq : g == 1 ? wk : g == 2 ? wv : wp;
    int idx = (blockIdx.x * 256 + threadIdx.x) * 4;
    float4 v = *(const float4*)(src + idx);
    s16x4 pk;
    pk[0] = (short)f2bf(v.x); pk[1] = (short)f2bf(v.y);
    pk[2] = (short)f2bf(v.z); pk[3] = (short)f2bf(v.w);
    *(s16x4*)(wbf + g * 65536 + idx) = pk;
}

// ---------------- GEMM core: 128o x 64n tile, BK=64, dbuf, global_load_lds ----------------
__device__ inline void gemm_core(const unsigned short* __restrict__ Wg,
                                 const unsigned short* __restrict__ Bg,
                                 int o0, int n0, int t, f32x4 (&acc)[4][2],
                                 unsigned short (*At)[128 * 64], unsigned short (*Bt)[64 * 64]) {
    int lane = t & 63, w = t >> 6, l15 = lane & 15, lg = lane >> 4;
    int wo = (w >> 1) * 64, wn = (w & 1) * 32;
    int aoff[4], boff[2];
    for (int i = 0; i < 4; ++i) {
        int p = i * 4096 + t * 16;
        int y = p ^ (((p >> 7) & 7) << 4);
        aoff[i] = (o0 + (y >> 7)) * 512 + (y & 127);
    }
    for (int i = 0; i < 2; ++i) {
        int p = i * 4096 + t * 16;
        int y = p ^ (((p >> 7) & 7) << 4);
        boff[i] = (n0 + (y >> 7)) * 512 + (y & 127);
    }
    const char* Wc = (const char*)Wg;
    const char* Bc = (const char*)Bg;
    int cur = 0;
    for (int i = 0; i < 4; ++i)
        load_lds16(Wc + aoff[i], (char*)At[0] + i * 4096 + w * 1024);
    for (int i = 0; i < 2; ++i)
        load_lds16(Bc + boff[i], (char*)Bt[0] + i * 4096 + w * 1024);
    __syncthreads();
    for (int s = 0; s < 4; ++s) {
        if (s < 3) {
            int k2 = (s + 1) * 128;   // k0 * 2 bytes
            for (int i = 0; i < 4; ++i)
                load_lds16(Wc + aoff[i] + k2, (char*)At[cur ^ 1] + i * 4096 + w * 1024);
            for (int i = 0; i < 2; ++i)
                load_lds16(Bc + boff[i] + k2, (char*)Bt[cur ^ 1] + i * 4096 + w * 1024);
        }
        const char* Al = (const char*)At[cur];
        const char* Bl = (const char*)Bt[cur];
        for (int kk = 0; kk < 2; ++kk) {
            s16x8 af[4], bfv[2];
            for (int mi = 0; mi < 4; ++mi) {
                int row = wo + mi * 16 + l15;
                int lo = row * 128 + kk * 64 + lg * 16;
                af[mi] = *(const s16x8*)(Al + (lo ^ ((row & 7) << 4)));
            }
            for (int ni = 0; ni < 2; ++ni) {
                int row = wn + ni * 16 + l15;
                int lo = row * 128 + kk * 64 + lg * 16;
                bfv[ni] = *(const s16x8*)(Bl + (lo ^ ((row & 7) << 4)));
            }
            for (int mi = 0; mi < 4; ++mi)
                for (int ni = 0; ni < 2; ++ni)
                    acc[mi][ni] = __builtin_amdgcn_mfma_f32_16x16x32_bf16(af[mi], bfv[ni], acc[mi][ni], 0, 0, 0);
        }
        __syncthreads();
        cur ^= 1;
    }
}

// ---------------- fused QKV GEMM (z = b*3 + g) ----------------
__global__ __launch_bounds__(256) void qkv_gemm_kernel(const unsigned short* __restrict__ wbf,
                                                       const float* __restrict__ bq,
                                                       const float* __restrict__ bk,
                                                       const float* __restrict__ bv,
                                                       const unsigned short* __restrict__ hn,
                                                       unsigned short* __restrict__ qt,
                                                       unsigned short* __restrict__ kt,
                                                       unsigned short* __restrict__ v2t) {
    __shared__ unsigned short At[2][128 * 64];
    __shared__ unsigned short Bt[2][64 * 64];
    int g = blockIdx.z % 3, b = blockIdx.z / 3;
    const float* bias = g == 0 ? bq : g == 1 ? bk : bv;
    float scale = g == 0 ? 0.0625f * LOG2E : 1.0f;
    int o0 = blockIdx.y * 128, n0 = blockIdx.x * 64;
    int t = threadIdx.x;
    const size_t sz = (size_t)N_ * C_;

    f32x4 acc[4][2];
    for (int mi = 0; mi < 4; ++mi)
        for (int ni = 0; ni < 2; ++ni)
            acc[mi][ni] = (f32x4){0.f, 0.f, 0.f, 0.f};
    gemm_core(wbf + g * 65536, hn + b * sz, o0, n0, t, acc, At, Bt);

    int lane = t & 63, w = t >> 6, l15 = lane & 15, lg = lane >> 4;
    int wo = (w >> 1) * 64, wn = (w & 1) * 32;
    for (int mi = 0; mi < 4; ++mi)
        for (int ni = 0; ni < 2; ++ni)
            for (int r = 0; r < 4; ++r) {
                int o = o0 + wo + mi * 16 + lg * 4 + r;
                int n = n0 + wn + ni * 16 + l15;
                float val = (acc[mi][ni][r] + bias[o]) * scale;
                if (g == 0) {
                    qt[b * sz + (size_t)n * C_ + o] = f2bf(val);
                } else if (g == 1) {
                    // slot = pi^-1(n&31): key bits (r=1:0, f=2, lg=4:3) -> s=16f+4lg+r
                    int slot = ((n >> 2) & 1) * 16 + ((n >> 3) & 3) * 4 + (n & 3);
                    kt[b * sz + (size_t)(n >> 5) * 8192 + (o >> 5) * 1024 + slot * 32 + (o & 31)] = f2bf(val);
                } else {
                    v2t[b * sz + (size_t)(n >> 5) * 8192 + o * 32 + (n & 31)] = f2bf(val);
                }
            }
}

// ---------------- output projection GEMM + residual ----------------
__global__ __launch_bounds__(256) void proj_gemm_kernel(const unsigned short* __restrict__ wbf,
                                                        const float* __restrict__ bp,
                                                        const unsigned short* __restrict__ ao,
                                                        const float* __restrict__ x,
                                                        float* __restrict__ out) {
    __shared__ unsigned short At[2][128 * 64];
    __shared__ unsigned short Bt[2][64 * 64];
    int b = blockIdx.z;
    int o0 = blockIdx.y * 128, n0 = blockIdx.x * 64;
    int t = threadIdx.x;
    const size_t sz = (size_t)N_ * C_;

    f32x4 acc[4][2];
    for (int mi = 0; mi < 4; ++mi)
        for (int ni = 0; ni < 2; ++ni)
            acc[mi][ni] = (f32x4){0.f, 0.f, 0.f, 0.f};
    gemm_core(wbf + 3 * 65536, ao + b * sz, o0, n0, t, acc, At, Bt);

    int lane = t & 63, w = t >> 6, l15 = lane & 15, lg = lane >> 4;
    int wo = (w >> 1) * 64, wn = (w & 1) * 32;
    for (int mi = 0; mi < 4; ++mi)
        for (int ni = 0; ni < 2; ++ni)
            for (int r = 0; r < 4; ++r) {
                int o = o0 + wo + mi * 16 + lg * 4 + r;
                int n = n0 + wn + ni * 16 + l15;
                size_t idx = b * sz + (size_t)o * N_ + n;
                out[idx] = x[idx] + acc[mi][ni][r] + bp[o];
            }
}

// ---------------- Flash attention: KV-split + LDS-staged fragment-major K/V ----------------
// qt: [b][n][c] (Q scaled by log2e/16). k3t: [b][m/32][c/32][32 slot][32 c]
// (slot s holds key m0+pi(s), pi(s)=8*((s>>2)&3)+4*((s>>4)&1)+(s&3)).
// v2t: [b][m/32][c][32]. Shfl-free softmax fast path: defer-max check uses
// per-lane local max only; lsum kept as per-lane partials, reduced once at end.
// Tile order phase-staggered per block (online softmax is order-invariant).
__global__ __launch_bounds__(256, 2) void attn_partial_kernel(const unsigned short* __restrict__ qt,
                                                              const unsigned short* __restrict__ k3t,
                                                              const unsigned short* __restrict__ v2t,
                                                              unsigned short* __restrict__ Opart,
                                                              float* __restrict__ ml,
                                                              int kvlen) {
    int b = blockIdx.z, split = blockIdx.y, nsplit = gridDim.y;
    int t = threadIdx.x, lane = t & 63, w = t >> 6, l15 = lane & 15, lg = lane >> 4;
    int n0 = (blockIdx.x * 4 + w) * 32;       // this wave's 32 query rows
    const size_t off = (size_t)b * N_ * C_;
    const unsigned short* Q = qt + off;
    const char* Kg = (const char*)(k3t + off);
    const char* Vg = (const char*)(v2t + off);

    __shared__ char Ktile[2][16384];
    __shared__ char Vtile[2][16384];

    s16x8 q[2][8];
    for (int qf = 0; qf < 2; ++qf)
        for (int kc = 0; kc < 8; ++kc)
            q[qf][kc] = *(const s16x8*)(Q + (size_t)(n0 + qf * 16 + l15) * C_ + kc * 32 + lg * 8);

    f32x4 O[2][16];
    for (int qf = 0; qf < 2; ++qf)
        for (int i = 0; i < 16; ++i) O[qf][i] = (f32x4){0.f, 0.f, 0.f, 0.f};
    float mrun[2] = {-1e30f, -1e30f};
    float lsum[2] = {0.f, 0.f};

    auto stage = [&](int buf, int tile) {
        const char* kg = Kg + (size_t)tile * 16384;
        const char* vg = Vg + (size_t)tile * 16384;
        for (int i = 0; i < 4; ++i)
            load_lds16(kg + i * 4096 + t * 16, Ktile[buf] + i * 4096 + w * 1024);
        for (int i = 0; i < 4; ++i)
            load_lds16(vg + i * 4096 + t * 16, Vtile[buf] + i * 4096 + w * 1024);
    };

    int niter = kvlen >> 5;                 // power of 2
    int mask = niter - 1;
    int tile0 = (split * kvlen) >> 5;
    int ph = (blockIdx.x * 5 + blockIdx.y * 3 + blockIdx.z) & mask;   // phase stagger
    int cur = 0;
    stage(0, tile0 + ph);
    __syncthreads();   // implicit vmcnt(0): first tile resident

    for (int it = 0; it < niter; ++it) {
        if (it + 1 < niter) stage(cur ^ 1, tile0 + ((it + 1 + ph) & mask));   // async prefetch

        const char* kb = Ktile[cur];
        const char* vb = Vtile[cur];

        // S^T = K' x Q : S[qf][f] lane holds q=l15, key pi(f*16+lg*4+r)=8lg+4f+r
        f32x4 S[2][2];
        for (int qf = 0; qf < 2; ++qf)
            for (int f = 0; f < 2; ++f) S[qf][f] = (f32x4){0.f, 0.f, 0.f, 0.f};
        for (int kc = 0; kc < 8; ++kc) {
            s16x8 k0 = *(const s16x8*)(kb + kc * 2048 + l15 * 64 + lg * 16);
            s16x8 k1 = *(const s16x8*)(kb + kc * 2048 + (16 + l15) * 64 + lg * 16);
            S[0][0] = __builtin_amdgcn_mfma_f32_16x16x32_bf16(k0, q[0][kc], S[0][0], 0, 0, 0);
            S[0][1] = __builtin_amdgcn_mfma_f32_16x16x32_bf16(k1, q[0][kc], S[0][1], 0, 0, 0);
            S[1][0] = __builtin_amdgcn_mfma_f32_16x16x32_bf16(k0, q[1][kc], S[1][0], 0, 0, 0);
            S[1][1] = __builtin_amdgcn_mfma_f32_16x16x32_bf16(k1, q[1][kc], S[1][1], 0, 0, 0);
        }

        // per-lane local max; no cross-lane ops on the fast path
        float lm[2];
        for (int qf = 0; qf < 2; ++qf)
            lm[qf] = fmaxf(fmaxf(fmaxf(S[qf][0][0], S[qf][0][1]), fmaxf(S[qf][0][2], S[qf][0][3])),
                           fmaxf(fmaxf(S[qf][1][0], S[qf][1][1]), fmaxf(S[qf][1][2], S[qf][1][3])));
        bool ok = (lm[0] <= mrun[0] + 11.0f) && (lm[1] <= mrun[1] + 11.0f);
        if (!__all(ok)) {
            // slow path: full per-row max reduce + uniform-per-row rescale
            for (int qf = 0; qf < 2; ++qf) {
                float m = lm[qf];
                m = fmaxf(m, __shfl_xor(m, 16));
                m = fmaxf(m, __shfl_xor(m, 32));
                float newm = fmaxf(mrun[qf], m);
                float alpha = __builtin_amdgcn_exp2f(mrun[qf] - newm);
                mrun[qf] = newm;
                lsum[qf] *= alpha;
                float a0 = __shfl(alpha, lg * 4 + 0);
                float a1 = __shfl(alpha, lg * 4 + 1);
                float a2 = __shfl(alpha, lg * 4 + 2);
                float a3 = __shfl(alpha, lg * 4 + 3);
                for (int i = 0; i < 16; ++i) {
                    O[qf][i][0] *= a0; O[qf][i][1] *= a1;
                    O[qf][i][2] *= a2; O[qf][i][3] *= a3;
                }
            }
        }

        // P = 2^(S-m): in-register A-frags + per-lane partial row sums
        s16x8 pa[2];
        for (int qf = 0; qf < 2; ++qf) {
            float p0 = __builtin_amdgcn_exp2f(S[qf][0][0] - mrun[qf]);
            float p1 = __builtin_amdgcn_exp2f(S[qf][0][1] - mrun[qf]);
            float p2 = __builtin_amdgcn_exp2f(S[qf][0][2] - mrun[qf]);
            float p3 = __builtin_amdgcn_exp2f(S[qf][0][3] - mrun[qf]);
            float p4 = __builtin_amdgcn_exp2f(S[qf][1][0] - mrun[qf]);
            float p5 = __builtin_amdgcn_exp2f(S[qf][1][1] - mrun[qf]);
            float p6 = __builtin_amdgcn_exp2f(S[qf][1][2] - mrun[qf]);
            float p7 = __builtin_amdgcn_exp2f(S[qf][1][3] - mrun[qf]);
            lsum[qf] += ((p0 + p1) + (p2 + p3)) + ((p4 + p5) + (p6 + p7));
            union { unsigned u[4]; s16x8 v; } pk;
            pk.u[0] = cvtpk(p0, p1);
            pk.u[1] = cvtpk(p2, p3);
            pk.u[2] = cvtpk(p4, p5);
            pk.u[3] = cvtpk(p6, p7);
            pa[qf] = pk.v;
        }

        // O += P * V  (V B-frags from LDS, shared across the two q-fragments)
        for (int cb = 0; cb < 16; ++cb) {
            s16x8 vf = *(const s16x8*)(vb + (cb * 16 + l15) * 64 + lg * 16);
            O[0][cb] = __builtin_amdgcn_mfma_f32_16x16x32_bf16(pa[0], vf, O[0][cb], 0, 0, 0);
            O[1][cb] = __builtin_amdgcn_mfma_f32_16x16x32_bf16(pa[1], vf, O[1][cb], 0, 0, 0);
        }

        __syncthreads();   // drains vmcnt(0): prefetch done, all waves done with cur
        cur ^= 1;
    }

    // finalize per-row l (one reduce for the whole kernel)
    for (int qf = 0; qf < 2; ++qf) {
        lsum[qf] += __shfl_xor(lsum[qf], 16);
        lsum[qf] += __shfl_xor(lsum[qf], 32);
    }

    unsigned short* Ob = Opart + (size_t)(b * nsplit + split) * N_ * C_;
    float* mlb = ml + (size_t)(b * nsplit + split) * N_ * 2;
    for (int qf = 0; qf < 2; ++qf)
        for (int cb = 0; cb < 16; ++cb)
            for (int r = 0; r < 4; ++r)
                Ob[(size_t)(n0 + qf * 16 + lg * 4 + r) * C_ + cb * 16 + l15] = f2bf(O[qf][cb][r]);
    if (lane < 16)
        for (int qf = 0; qf < 2; ++qf) {
            int n = n0 + qf * 16 + lane;
            mlb[n * 2] = mrun[qf];
            mlb[n * 2 + 1] = lsum[qf];
        }
}

// ---------------- merge partials -> ao bf16 [b][n][c] ----------------
__global__ __launch_bounds__(256) void attn_merge_kernel(const unsigned short* __restrict__ Opart,
                                                         const float* __restrict__ ml,
                                                         unsigned short* __restrict__ ao,
                                                         int nsplit) {
    int b = blockIdx.y, n = blockIdx.x, c = threadIdx.x;
    float M = -1e30f;
    for (int s = 0; s < nsplit; ++s)
        M = fmaxf(M, ml[((size_t)(b * nsplit + s) * N_ + n) * 2]);
    float L = 0.f, o = 0.f;
    for (int s = 0; s < nsplit; ++s) {
        const float* mlp = ml + ((size_t)(b * nsplit + s) * N_ + n) * 2;
        float wgt = __builtin_amdgcn_exp2f(mlp[0] - M);
        L += mlp[1] * wgt;
        o += bf2f(Opart[((size_t)(b * nsplit + s) * N_ + n) * C_ + c]) * wgt;
    }
    ao[((size_t)b * N_ + n) * C_ + c] = f2bf(o / L);
}

extern "C" void kernel_launch(void* const* d_in, const int* in_sizes, int n_in,
                              void* d_out, int out_size, void* d_ws, size_t ws_size,
                              hipStream_t stream) {
    const float* x = (const float*)d_in[0];
    const float* gamma = (const float*)d_in[1];
    const float* beta = (const float*)d_in[2];
    const float* wq = (const float*)d_in[3];
    const float* bq = (const float*)d_in[4];
    const float* wk = (const float*)d_in[5];
    const float* bk = (const float*)d_in[6];
    const float* wv = (const float*)d_in[7];
    const float* bv = (const float*)d_in[8];
    const float* wp = (const float*)d_in[9];
    const float* bp = (const float*)d_in[10];
    float* out = (float*)d_out;

    const size_t sz = (size_t)B_ * N_ * C_;
    unsigned short* hn = (unsigned short*)d_ws;  // [b][n][c]
    unsigned short* qt = hn + sz;                // [b][n][c], scaled by log2e/16
    unsigned short* kt = qt + sz;                // k3t fragment-major layout
    unsigned short* v2t = kt + sz;               // [b][m/32][c][32]
    unsigned short* ao = v2t + sz;               // [b][n][c]
    unsigned short* wbf = ao + sz;               // 4 x 256 x 256 bf16
    unsigned short* Opart = wbf + 4 * 65536;     // [b][s][n][c] bf16, unnormalized
    int nsplit = 8;
    while (nsplit > 1 &&
           (5 * sz + 262144 + (size_t)nsplit * sz) * 2 + (size_t)nsplit * B_ * N_ * 8 + 4096 > ws_size)
        nsplit >>= 1;
    float* ml = (float*)(Opart + (size_t)nsplit * sz);   // [b][s][n][2] (log2-domain m, l)
    float* part = ml + (size_t)nsplit * B_ * N_ * 2;     // [256][2] GN partial sums

    hipLaunchKernelGGL(gn_stats_kernel, dim3(256), dim3(256), 0, stream, x, part);
    hipLaunchKernelGGL(wcvt_kernel, dim3(64, 4), dim3(256), 0, stream, wq, wk, wv, wp, wbf);
    hipLaunchKernelGGL(gn_apply_kernel, dim3(256), dim3(256), 0, stream, x, gamma, beta, part, hn);
    hipLaunchKernelGGL(qkv_gemm_kernel, dim3(64, 2, 6), dim3(256), 0, stream,
                       wbf, bq, bk, bv, hn, qt, kt, v2t);
    hipLaunchKernelGGL(attn_partial_kernel, dim3(32, nsplit, 2), dim3(256), 0, stream,
                       qt, kt, v2t, Opart, ml, N_ / nsplit);
    hipLaunchKernelGGL(attn_merge_kernel, dim3(N_, 2), dim3(256), 0, stream, Opart, ml, ao, nsplit);
    hipLaunchKernelGGL(proj_gemm_kernel, dim3(64, 2, 2), dim3(256), 0, stream, wbf, bp, ao, x, out);
}